// Round 1
// baseline (3512.363 us; speedup 1.0000x reference)
//
#include <hip/hip_runtime.h>

#define N_NODES 100000
#define N_EDGES 1600000
#define F 64

// ---------------- tiny setup kernels ----------------

__global__ void k_sig(const float* __restrict__ ls0, const float* __restrict__ ls1,
                      float* __restrict__ sig0, float* __restrict__ sig1) {
    int i = threadIdx.x;
    if (i < 64)        sig0[i]      = expf(ls0[i]);
    else if (i < 128)  sig1[i - 64] = expf(ls1[i - 64]);
}

__global__ void k_deg(const int* __restrict__ src, const int* __restrict__ dst,
                      int* __restrict__ degO, int* __restrict__ degI) {
    int i = blockIdx.x * blockDim.x + threadIdx.x;
    int stride = gridDim.x * blockDim.x;
    for (; i < N_EDGES; i += stride) {
        atomicAdd(&degO[src[i]], 1);
        atomicAdd(&degI[dst[i]], 1);
    }
}

__global__ void k_norm(const int* __restrict__ degO, const int* __restrict__ degI,
                       float* __restrict__ normO, float* __restrict__ normI) {
    int i = blockIdx.x * blockDim.x + threadIdx.x;
    if (i < N_NODES) {
        int dO = degO[i], dI = degI[i];
        normO[i] = dO > 0 ? rsqrtf((float)dO) : 0.0f;
        normI[i] = dI > 0 ? rsqrtf((float)dI) : 0.0f;
    }
}

// xs = x * norm_out, vectorized float4 (16 chunks of 4 floats per node row)
__global__ void k_scale_x(const float4* __restrict__ x, const float* __restrict__ normO,
                          float4* __restrict__ xs) {
    int i = blockIdx.x * blockDim.x + threadIdx.x;
    int stride = gridDim.x * blockDim.x;
    const int total = N_NODES * (F / 4);
    for (; i < total; i += stride) {
        int node = i >> 4;
        float n = normO[node];
        float4 v = x[i];
        v.x *= n; v.y *= n; v.z *= n; v.w *= n;
        xs[i] = v;
    }
}

// ---------------- edge scatter kernel ----------------
// Each thread owns one 16B feature chunk (c = tid&15) of one edge.
// eps reads fully coalesced (1KB per wave-instruction across 4 edges).
// xs gather: 256B rows, L3-resident. Scatter via HW f32 atomics.
__global__ __launch_bounds__(256) void k_edge(
        const float4* __restrict__ xs, const float4* __restrict__ eps,
        const int* __restrict__ src, const int* __restrict__ dst,
        const float* __restrict__ amu, const float* __restrict__ sig,
        float* __restrict__ agg) {
    long long tid = (long long)blockIdx.x * blockDim.x + threadIdx.x;
    long long stride = (long long)gridDim.x * blockDim.x;   // multiple of 16
    const long long total = (long long)N_EDGES * (F / 4);
    int c = (int)(tid & 15);
    float4 am = ((const float4*)amu)[c];
    float4 sg = ((const float4*)sig)[c];
    for (long long t = tid; t < total; t += stride) {
        int e = (int)(t >> 4);
        int s = src[e];
        int d = dst[e];
        float4 ev = eps[t];
        float4 xv = xs[(long long)s * 16 + c];
        float4 m;
        m.x = xv.x * fmaf(sg.x, ev.x, am.x);
        m.y = xv.y * fmaf(sg.y, ev.y, am.y);
        m.z = xv.z * fmaf(sg.z, ev.z, am.z);
        m.w = xv.w * fmaf(sg.w, ev.w, am.w);
        float* ap = agg + (long long)d * F + c * 4;
        unsafeAtomicAdd(ap + 0, m.x);
        unsafeAtomicAdd(ap + 1, m.y);
        unsafeAtomicAdd(ap + 2, m.z);
        unsafeAtomicAdd(ap + 3, m.w);
    }
}

// ---------------- fused (agg*normI)@W + b, relu, *normO ----------------
// One wave per row; W staged in LDS; row broadcast via __shfl.
__global__ __launch_bounds__(256) void k_mid(
        const float* __restrict__ agg, const float* __restrict__ normI,
        const float* __restrict__ normO, const float* __restrict__ W,
        const float* __restrict__ b, float* __restrict__ out) {
    __shared__ float Ws[F * F];
    for (int i = threadIdx.x; i < F * F; i += blockDim.x) Ws[i] = W[i];
    __syncthreads();
    int lane = threadIdx.x & 63;
    int wave = threadIdx.x >> 6;
    int rpb = blockDim.x >> 6;
    for (int r = blockIdx.x * rpb + wave; r < N_NODES; r += gridDim.x * rpb) {
        float v = agg[(long long)r * F + lane] * normI[r];
        float acc = b[lane];
#pragma unroll
        for (int k = 0; k < F; ++k)
            acc = fmaf(__shfl(v, k), Ws[k * F + lane], acc);
        acc = fmaxf(acc, 0.0f) * normO[r];
        out[(long long)r * F + lane] = acc;
    }
}

// ---------------- fused (agg*normI)@W + b, row softmax ----------------
__global__ __launch_bounds__(256) void k_out(
        const float* __restrict__ agg, const float* __restrict__ normI,
        const float* __restrict__ W, const float* __restrict__ b,
        float* __restrict__ out) {
    __shared__ float Ws[F * F];
    for (int i = threadIdx.x; i < F * F; i += blockDim.x) Ws[i] = W[i];
    __syncthreads();
    int lane = threadIdx.x & 63;
    int wave = threadIdx.x >> 6;
    int rpb = blockDim.x >> 6;
    for (int r = blockIdx.x * rpb + wave; r < N_NODES; r += gridDim.x * rpb) {
        float v = agg[(long long)r * F + lane] * normI[r];
        float acc = b[lane];
#pragma unroll
        for (int k = 0; k < F; ++k)
            acc = fmaf(__shfl(v, k), Ws[k * F + lane], acc);
        // wave softmax across 64 lanes
        float mx = acc;
#pragma unroll
        for (int off = 32; off > 0; off >>= 1) mx = fmaxf(mx, __shfl_xor(mx, off));
        float ex = __expf(acc - mx);
        float sm = ex;
#pragma unroll
        for (int off = 32; off > 0; off >>= 1) sm += __shfl_xor(sm, off);
        out[(long long)r * F + lane] = ex / sm;
    }
}

// ---------------- launch ----------------

extern "C" void kernel_launch(void* const* d_in, const int* in_sizes, int n_in,
                              void* d_out, int out_size, void* d_ws, size_t ws_size,
                              hipStream_t stream) {
    const float* x    = (const float*)d_in[0];
    const int*   src  = (const int*)d_in[1];
    const int*   dst  = (const int*)d_in[2];
    const float* amu0 = (const float*)d_in[3];
    const float* als0 = (const float*)d_in[4];
    const float* amu1 = (const float*)d_in[5];
    const float* als1 = (const float*)d_in[6];
    const float* W0   = (const float*)d_in[7];
    const float* b0   = (const float*)d_in[8];
    const float* W1   = (const float*)d_in[9];
    const float* b1   = (const float*)d_in[10];
    const float* eps0 = (const float*)d_in[11];
    const float* eps1 = (const float*)d_in[12];
    float* out = (float*)d_out;

    char* ws = (char*)d_ws;
    int*   degO  = (int*)(ws + 0);
    int*   degI  = (int*)(ws + 400000);
    float* normO = (float*)(ws + 800000);
    float* normI = (float*)(ws + 1200000);
    float* sig0  = (float*)(ws + 1600000);
    float* sig1  = (float*)(ws + 1600256);
    float* bufA  = (float*)(ws + 2000000);              // xs, later agg1
    float* bufB  = (float*)(ws + 2000000 + 25600000);   // agg0, later h1s
    // total ws use: ~53.2 MB

    // zero degree counters + agg0
    hipMemsetAsync(ws, 0, 800000, stream);
    hipMemsetAsync(bufB, 0, 25600000, stream);

    k_sig<<<1, 128, 0, stream>>>(als0, als1, sig0, sig1);
    k_deg<<<2048, 256, 0, stream>>>(src, dst, degO, degI);
    k_norm<<<(N_NODES + 255) / 256, 256, 0, stream>>>(degO, degI, normO, normI);
    k_scale_x<<<2048, 256, 0, stream>>>((const float4*)x, normO, (float4*)bufA);

    // layer 0 edges: agg0 (bufB) += (x*normO)[src] * (mu0 + sig0*eps0)
    k_edge<<<2048, 256, 0, stream>>>((const float4*)bufA, (const float4*)eps0,
                                     src, dst, amu0, sig0, bufB);

    // zero agg1 (reuses bufA; ordered after k_edge read of xs)
    hipMemsetAsync(bufA, 0, 25600000, stream);

    // h1s (in-place in bufB) = relu((agg0*normI)@W0 + b0) * normO
    k_mid<<<2048, 256, 0, stream>>>(bufB, normI, normO, W0, b0, bufB);

    // layer 1 edges: agg1 (bufA) += h1s[src] * (mu1 + sig1*eps1)
    k_edge<<<2048, 256, 0, stream>>>((const float4*)bufB, (const float4*)eps1,
                                     src, dst, amu1, sig1, bufA);

    // out = softmax((agg1*normI)@W1 + b1)
    k_out<<<2048, 256, 0, stream>>>(bufA, normI, W1, b1, out);
}